// Round 1
// baseline (698.825 us; speedup 1.0000x reference)
//
#include <hip/hip_runtime.h>

// Fused: status = softmax(embs @ W_status^T + b_status)   (5)
//        flight = softmax(embs @ W_flight^T + b_flight)   (30)
//        out    = [s0, s2, s1, s4*flight[0..29], s3*flight[0..29]]  (63)
//
// Layout: 64 rows per block, 256 threads = 4 waves; wave = K-part (256 elems),
// lane = row. W reads are wave-uniform -> scalar loads (constant cache).
// Partial dot products reduced across waves via LDS; wave 0 does the
// softmax epilogue and writes 63 floats per row.

#define ROWS_PER_BLOCK 64

__global__ __launch_bounds__(256, 4)
void fused_heads_kernel(const float* __restrict__ embs,
                        const float* __restrict__ W_status,
                        const float* __restrict__ b_status,
                        const float* __restrict__ W_flight,
                        const float* __restrict__ b_flight,
                        float* __restrict__ out) {
    // red[part-1][lane][o], pitch 36 so float4 writes are conflict-free
    __shared__ float red[3][64][36];

    const int tid  = threadIdx.x;
    const int lane = tid & 63;
    const int part = tid >> 6;                 // 0..3, K-chunk of 256
    const int row  = blockIdx.x * ROWS_PER_BLOCK + lane;

    const float4* ef4 = (const float4*)embs + (size_t)row * 256 + part * 64;
    const float4* Ws4 = (const float4*)W_status;   // [5][256] float4
    const float4* Wf4 = (const float4*)W_flight;   // [30][256] float4

    float acc[36];
#pragma unroll
    for (int o = 0; o < 36; ++o) acc[o] = 0.0f;

    const int cb = part * 64;
#pragma unroll 1
    for (int c = 0; c < 64; ++c) {
        const float4 v = ef4[c];
        const int wc = cb + c;                 // wave-uniform
#pragma unroll
        for (int o = 0; o < 5; ++o) {
            const float4 w = Ws4[o * 256 + wc];
            float a = acc[o];
            a = fmaf(v.x, w.x, a);
            a = fmaf(v.y, w.y, a);
            a = fmaf(v.z, w.z, a);
            a = fmaf(v.w, w.w, a);
            acc[o] = a;
        }
#pragma unroll
        for (int o = 0; o < 30; ++o) {
            const float4 w = Wf4[o * 256 + wc];
            float a = acc[5 + o];
            a = fmaf(v.x, w.x, a);
            a = fmaf(v.y, w.y, a);
            a = fmaf(v.z, w.z, a);
            a = fmaf(v.w, w.w, a);
            acc[5 + o] = a;
        }
    }

    // ---- cross-part reduction via LDS ----
    if (part != 0) {
        float4* dst = (float4*)&red[part - 1][lane][0];
#pragma unroll
        for (int j = 0; j < 9; ++j) {
            dst[j] = make_float4(acc[4*j], acc[4*j+1], acc[4*j+2], acc[4*j+3]);
        }
    }
    __syncthreads();

    if (part == 0) {
#pragma unroll
        for (int p = 0; p < 3; ++p) {
            const float4* src = (const float4*)&red[p][lane][0];
#pragma unroll
            for (int j = 0; j < 9; ++j) {
                const float4 t = src[j];
                acc[4*j]     += t.x;
                acc[4*j + 1] += t.y;
                acc[4*j + 2] += t.z;
                acc[4*j + 3] += t.w;
            }
        }

        // ---- status softmax (5) ----
        float s[5];
#pragma unroll
        for (int j = 0; j < 5; ++j) s[j] = acc[j] + b_status[j];
        float ms = s[0];
#pragma unroll
        for (int j = 1; j < 5; ++j) ms = fmaxf(ms, s[j]);
        float sums = 0.0f;
#pragma unroll
        for (int j = 0; j < 5; ++j) { s[j] = __expf(s[j] - ms); sums += s[j]; }
        const float invs = 1.0f / sums;

        // ---- flight softmax (30) ----
#pragma unroll
        for (int j = 0; j < 30; ++j) acc[5 + j] += b_flight[j];
        float mf = acc[5];
#pragma unroll
        for (int j = 1; j < 30; ++j) mf = fmaxf(mf, acc[5 + j]);
        float sumf = 0.0f;
#pragma unroll
        for (int j = 0; j < 30; ++j) { acc[5 + j] = __expf(acc[5 + j] - mf); sumf += acc[5 + j]; }
        const float invf = 1.0f / sumf;

        // ---- write 63 outputs ----
        float* orow = out + (size_t)row * 63;
        orow[0] = s[0] * invs;                       // no_flight  (status 0)
        orow[1] = s[2] * invs;                       // cancel     (status 2)
        orow[2] = s[1] * invs;                       // no_reservation (status 1)
        const float book   = s[4] * invs * invf;     // status 4
        const float change = s[3] * invs * invf;     // status 3
#pragma unroll
        for (int j = 0; j < 30; ++j) {
            orow[3 + j]  = book   * acc[5 + j];
            orow[33 + j] = change * acc[5 + j];
        }
    }
}

extern "C" void kernel_launch(void* const* d_in, const int* in_sizes, int n_in,
                              void* d_out, int out_size, void* d_ws, size_t ws_size,
                              hipStream_t stream) {
    const float* embs     = (const float*)d_in[0];
    const float* W_status = (const float*)d_in[1];
    const float* b_status = (const float*)d_in[2];
    const float* W_flight = (const float*)d_in[3];
    const float* b_flight = (const float*)d_in[4];
    float* out = (float*)d_out;

    const int rows = in_sizes[0] / 1024;             // 65536
    const int grid = rows / ROWS_PER_BLOCK;          // 1024

    fused_heads_kernel<<<grid, 256, 0, stream>>>(
        embs, W_status, b_status, W_flight, b_flight, out);
}